// Round 3
// baseline (716.056 us; speedup 1.0000x reference)
//
#include <hip/hip_runtime.h>
#include <hip/hip_bf16.h>
#include <math.h>

typedef __bf16 bf16;
typedef __bf16 bf16x4 __attribute__((ext_vector_type(4)));
typedef __bf16 bf16x8 __attribute__((ext_vector_type(8)));
typedef float floatx4 __attribute__((ext_vector_type(4)));

#define BB 2
#define LL 1024
#define DD 768
#define DI 1536
#define MROWS 2048   // B*L
#define NXP 80       // dt_rank + 2*d_state
#define DTRANK 48
#define DTPAD 64     // dt K padded to 64
#define DSTATE 16
#define NC 16        // scan chunks
#define CLEN 64      // scan chunk length (NC*CLEN == LL)
#define KSPLIT 16    // x_proj split-K factor (K-seg = 96)
#define OPKS 4       // out_proj split-K factor (K-seg = 384)
#define LOG2E 1.4426950408889634f
#define TROW 132     // floats per sdpT/sbcT row (128 data + 4 pad)
#define SPL 276      // floats per sP l-slot (16 d * 17 + pad)

// async global->LDS, 16 B per lane; lds dest must be wave-uniform base (+lane*16)
__device__ __forceinline__ void ld16(void* lds, const void* g) {
    __builtin_amdgcn_global_load_lds(
        (const __attribute__((address_space(1))) void*)g,
        (__attribute__((address_space(3))) void*)lds, 16, 0, 0);
}

// drain this wave's outstanding async global_load_lds before signalling barrier.
__device__ __forceinline__ void wait_vm0() {
    asm volatile("s_waitcnt vmcnt(0)" ::: "memory");
}

// raw v_exp_f32 (no ocml denormal fixup; exp2(x<-126) flushes to 0 which is fine here)
__device__ __forceinline__ float exp2_raw(float x) {
#if __has_builtin(__builtin_amdgcn_exp2f)
    return __builtin_amdgcn_exp2f(x);
#else
    float r; asm("v_exp_f32 %0, %1" : "=v"(r) : "v"(x)); return r;
#endif
}

// ---------------------------------------------------------------- all weight cvt in one kernel
#define N1 (4 * 3072 * 768)
#define N2 (4 * NXP * DI)
#define N3 (4 * DI * DTPAD)
#define N4 (4 * DD * DI)
__global__ __launch_bounds__(256) void cvt_all_k(const float* __restrict__ in_proj_w,
                                                 const float* __restrict__ x_proj_w,
                                                 const float* __restrict__ dt_proj_w,
                                                 const float* __restrict__ out_proj_w,
                                                 bf16* __restrict__ w_in,
                                                 bf16* __restrict__ w_xp,
                                                 bf16* __restrict__ w_dt,
                                                 bf16* __restrict__ w_out) {
    int i = blockIdx.x * 256 + threadIdx.x;
    if (i < N1) { w_in[i] = (bf16)in_proj_w[i]; return; }
    i -= N1;
    if (i < N2) { w_xp[i] = (bf16)x_proj_w[i]; return; }
    i -= N2;
    if (i < N3) {
        int row = i >> 6, c = i & 63;
        w_dt[i] = (c < DTRANK) ? (bf16)dt_proj_w[row * DTRANK + c] : (bf16)0.f;
        return;
    }
    i -= N3;
    if (i < N4) w_out[i] = (bf16)out_proj_w[i];
}

// ---------------------------------------------------------------- rmsnorm -> bf16 (layer 0 only)
__global__ __launch_bounds__(256) void rmsnorm_k(const float* __restrict__ x,
                                                 const float* __restrict__ w,
                                                 bf16* __restrict__ out) {
    int row = blockIdx.x;
    const float* xr = x + (size_t)row * DD;
    int tid = threadIdx.x;
    float v[3]; float ss = 0.f;
    for (int j = 0; j < 3; j++) { v[j] = xr[tid + j * 256]; ss += v[j] * v[j]; }
    for (int o = 1; o < 64; o <<= 1) ss += __shfl_xor(ss, o, 64);
    __shared__ float sred[4];
    if ((tid & 63) == 0) sred[tid >> 6] = ss;
    __syncthreads();
    float scale = rsqrtf((sred[0] + sred[1] + sred[2] + sred[3]) / (float)DD + 1e-6f);
    for (int j = 0; j < 3; j++) {
        int c = tid + j * 256;
        out[(size_t)row * DD + c] = (bf16)(v[j] * scale * w[c]);
    }
}

// ---------------------------------------------------------------- GEMM: C = A @ W^T
// MODE 1: store bf16 | MODE 5: split-K partials f32
template <int MODE>
__global__ __launch_bounds__(256) void gemm_bt(const bf16* __restrict__ A,
                                               const bf16* __restrict__ W,
                                               float* __restrict__ Cf,
                                               bf16* __restrict__ Cb,
                                               int M, int N, int K) {
    __shared__ bf16 As[128][32];
    __shared__ bf16 Ws[128][32];
    const int tid  = threadIdx.x;
    const int m0   = blockIdx.x * 128;
    const int n0   = blockIdx.y * 128;
    const int wave = tid >> 6;
    const int lane = tid & 63;
    const int wm   = (wave >> 1) * 64;
    const int wn   = (wave & 1) * 64;
    const int lrow = lane & 15;
    const int quad = lane >> 4;

    int kbeg = 0, kend = K;
    if constexpr (MODE == 5) {
        int kseg = K / gridDim.z;
        kbeg = blockIdx.z * kseg;
        kend = kbeg + kseg;
        Cf  += (size_t)blockIdx.z * M * N;
    }

    floatx4 acc[4][4];
    for (int mi = 0; mi < 4; mi++)
        for (int ni = 0; ni < 4; ni++) acc[mi][ni] = (floatx4){0.f, 0.f, 0.f, 0.f};

    const int r0  = tid >> 2;        // 0..63
    const int r1  = r0 + 64;         // 64..127
    const int seg = (tid & 3) * 8;   // 0,8,16,24
    char* asb0 = (char*)As + wave * 1024;
    char* asb1 = (char*)As + 4096 + wave * 1024;
    char* wsb0 = (char*)Ws + wave * 1024;
    char* wsb1 = (char*)Ws + 4096 + wave * 1024;

    for (int kb = kbeg; kb < kend; kb += 32) {
        int gk = kb + seg;
        __syncthreads();   // previous iteration's LDS reads done
        ld16(asb0, A + (size_t)(m0 + r0) * K + gk);
        ld16(asb1, A + (size_t)(m0 + r1) * K + gk);
        ld16(wsb0, W + (size_t)(n0 + r0) * K + gk);
        ld16(wsb1, W + (size_t)(n0 + r1) * K + gk);
        wait_vm0();        // this wave's async LDS fills landed
        __syncthreads();   // all waves' fills landed -> tiles ready
        bf16x8 af[4], wf[4];
        for (int mi = 0; mi < 4; mi++) af[mi] = *(const bf16x8*)&As[wm + mi * 16 + lrow][quad * 8];
        for (int ni = 0; ni < 4; ni++) wf[ni] = *(const bf16x8*)&Ws[wn + ni * 16 + lrow][quad * 8];
        for (int mi = 0; mi < 4; mi++)
            for (int ni = 0; ni < 4; ni++)
                acc[mi][ni] = __builtin_amdgcn_mfma_f32_16x16x32_bf16(af[mi], wf[ni], acc[mi][ni], 0, 0, 0);
    }
    for (int mi = 0; mi < 4; mi++) {
        int rowb = m0 + wm + mi * 16 + quad * 4;
        for (int ni = 0; ni < 4; ni++) {
            int col = n0 + wn + ni * 16 + lrow;
            for (int r = 0; r < 4; r++) {
                int row = rowb + r;
                float v = acc[mi][ni][r];
                if constexpr (MODE == 1) Cb[(size_t)row * N + col] = (bf16)v;
                else                     Cf[(size_t)row * N + col] = v;
            }
        }
    }
}

// ---------------------------------------------------------------- out_proj partials + residual + NEXT layer rmsnorm (fused)
__global__ __launch_bounds__(256) void op_reduce_norm_k(const float* __restrict__ part,
                                                        const float* __restrict__ resid,
                                                        const float* __restrict__ nw,
                                                        float* __restrict__ xout,
                                                        bf16* __restrict__ xnb) {
    int row = blockIdx.x;
    int tid = threadIdx.x;
    float v[3]; float ss = 0.f;
    for (int j = 0; j < 3; j++) {
        int c = tid + j * 256;
        size_t idx = (size_t)row * DD + c;
        float s = resid[idx];
        for (int ks = 0; ks < OPKS; ks++) s += part[(size_t)ks * MROWS * DD + idx];
        v[j] = s;
        xout[idx] = s;
        ss += s * s;
    }
    for (int o = 1; o < 64; o <<= 1) ss += __shfl_xor(ss, o, 64);
    __shared__ float sred[4];
    if ((tid & 63) == 0) sred[tid >> 6] = ss;
    __syncthreads();
    float scale = rsqrtf((sred[0] + sred[1] + sred[2] + sred[3]) / (float)DD + 1e-6f);
    for (int j = 0; j < 3; j++) {
        int c = tid + j * 256;
        xnb[(size_t)row * DD + c] = (bf16)(v[j] * scale * nw[c]);
    }
}

// ---------------------------------------------------------------- x_proj split-K GEMM
__global__ __launch_bounds__(256) void gemm_xp(const bf16* __restrict__ A,
                                               const bf16* __restrict__ W,
                                               float* __restrict__ part) {
    __shared__ bf16 As[64][40];
    __shared__ bf16 Ws[128][40];
    const int tid  = threadIdx.x;
    const int m0   = blockIdx.x * 64;
    const int ks   = blockIdx.y;
    const int k0   = ks * (DI / KSPLIT);
    const int wave = tid >> 6;
    const int lane = tid & 63;
    const int lrow = lane & 15;
    const int quad = lane >> 4;
    const int wm   = wave * 16;

    floatx4 acc[5];
    for (int ni = 0; ni < 5; ni++) acc[ni] = (floatx4){0.f, 0.f, 0.f, 0.f};

    const int ra  = tid >> 2;
    const int rw1 = ra + 64;
    const int seg = (tid & 3) * 8;

    for (int kb = 0; kb < DI / KSPLIT; kb += 32) {
        int gk = k0 + kb + seg;
        bf16x8 va = *(const bf16x8*)(A + (size_t)(m0 + ra) * DI + gk);
        bf16x8 vw0, vw1;
        if (ra < NXP) vw0 = *(const bf16x8*)(W + (size_t)ra * DI + gk);
        else          for (int j = 0; j < 8; j++) vw0[j] = (bf16)0.f;
        if (rw1 < NXP) vw1 = *(const bf16x8*)(W + (size_t)rw1 * DI + gk);
        else           for (int j = 0; j < 8; j++) vw1[j] = (bf16)0.f;
        __syncthreads();
        *(bf16x8*)&As[ra][seg]  = va;
        *(bf16x8*)&Ws[ra][seg]  = vw0;
        *(bf16x8*)&Ws[rw1][seg] = vw1;
        __syncthreads();
        bf16x8 af = *(const bf16x8*)&As[wm + lrow][quad * 8];
        for (int ni = 0; ni < 5; ni++) {
            bf16x8 wf = *(const bf16x8*)&Ws[ni * 16 + lrow][quad * 8];
            acc[ni] = __builtin_amdgcn_mfma_f32_16x16x32_bf16(af, wf, acc[ni], 0, 0, 0);
        }
    }
    float* pout = part + (size_t)ks * MROWS * NXP;
    for (int ni = 0; ni < 5; ni++) {
        int col = ni * 16 + lrow;
        for (int r = 0; r < 4; r++) {
            int row = m0 + wm + quad * 4 + r;
            pout[(size_t)row * NXP + col] = acc[ni][r];
        }
    }
}

// reduce split-K partials -> xdbl f32 + padded bf16 dt
__global__ __launch_bounds__(256) void xp_reduce_k(const float* __restrict__ part,
                                                   float* __restrict__ xdbl,
                                                   bf16* __restrict__ dtbf) {
    int idx = blockIdx.x * 256 + threadIdx.x;
    if (idx >= MROWS * NXP) return;
    float s = 0.f;
    for (int j = 0; j < KSPLIT; j++) s += part[(size_t)j * MROWS * NXP + idx];
    xdbl[idx] = s;
    int m = idx / NXP, c = idx - m * NXP;
    if (c < DTRANK)      dtbf[m * DTPAD + c] = (bf16)s;
    else if (c < DTPAD)  dtbf[m * DTPAD + c] = (bf16)0.f;
}

// ---------------------------------------------------------------- causal depthwise conv + silu + gate (4-wide, bf16 outputs)
__global__ __launch_bounds__(256) void conv_silu_k(const bf16* __restrict__ xz,
                                                   const float* __restrict__ cw,
                                                   const float* __restrict__ cb,
                                                   bf16* __restrict__ xcb,
                                                   bf16* __restrict__ gzb) {
    int t = blockIdx.x * 256 + threadIdx.x;
    if (t >= MROWS * (DI / 4)) return;
    int m = t / (DI / 4);
    int d = (t - m * (DI / 4)) * 4;
    int l = m & (LL - 1);
    float acc[4];
    floatx4 cwv[4];
    for (int q = 0; q < 4; q++) {
        acc[q] = cb[d + q];
        cwv[q] = *(const floatx4*)&cw[(d + q) * 4];
    }
    for (int k = 0; k < 4; k++) {
        int lp = l - 3 + k;
        if (lp >= 0) {
            bf16x4 v = *(const bf16x4*)&xz[(size_t)(m - 3 + k) * (2 * DI) + d];
            for (int q = 0; q < 4; q++) acc[q] += (float)v[q] * cwv[q][k];
        }
    }
    bf16x4 xo, go;
    bf16x4 z4 = *(const bf16x4*)&xz[(size_t)m * (2 * DI) + DI + d];
    for (int q = 0; q < 4; q++) {
        float s = acc[q] / (1.f + __expf(-acc[q]));
        xo[q] = (bf16)s;
        float zv = (float)z4[q];
        go[q] = (bf16)(zv / (1.f + __expf(-zv)));
    }
    *(bf16x4*)&xcb[(size_t)m * DI + d] = xo;
    *(bf16x4*)&gzb[(size_t)m * DI + d] = go;
}

// ---------------------------------------------------------------- single-pass sequential selective scan
// v3: kill the per-iteration DPP row-reduce (16 cyc issue + 4-deep serial chain
// per step, ~half the scan cost at 1 wave/SIMD). Each lane now does ONE
// ds_write_b32 of h*C into sP[16l][16d][16n] (stride-17 pad, <=2-way conflicts);
// after each 16-step group a reduce pass (thread -> (l,d), 16 contiguous b32
// reads + adjacent-pair add tree == bitwise-identical to the DPP butterfly)
// computes y, applies skip/gate and stores to global. sP is double-buffered so
// reduce(g-1) interleaves with scan(g) for ILP. Emit phase + syT are gone.
__global__ __launch_bounds__(256) void scan_k(const bf16* __restrict__ dtb,
                                              const bf16* __restrict__ wdt,
                                              const float* __restrict__ dtbias,
                                              const bf16* __restrict__ xcb,
                                              const bf16* __restrict__ gzb,
                                              const float* __restrict__ xdbl,
                                              const float* __restrict__ A_log,
                                              const float* __restrict__ Dskip,
                                              bf16* __restrict__ ybf) {
    const int b   = blockIdx.y;
    const int d0  = blockIdx.x * 16;
    const int tid = threadIdx.x;
    const int dl  = tid >> 4;          // scan: d row   | reduce: l-slot
    const int n   = tid & 15;          // scan: state n | reduce: d col
    const int wv  = tid >> 6;
    const int lane = tid & 63;
    const int lr  = lane & 15;         // delta-phase d / C-col
    const int q   = lane >> 4;         // 0..3

    const float a2  = -__expf(A_log[(size_t)(d0 + dl) * DSTATE + n]) * LOG2E;
    const float bi  = dtbias[d0 + lr];
    const float dsk = Dskip[d0 + lr];

    __shared__ __align__(16) bf16  Bdt[16][72];        // w_dt tile (persistent)
    __shared__ __align__(16) bf16  Adt[CLEN][64];      // dt rows, XOR-swizzled cols (DMA)
    __shared__ __align__(16) float sbcraw[CLEN][32];   // raw B|C (DMA)
    __shared__ __align__(16) bf16  sxc[CLEN][16];      // conv out (DMA)
    __shared__ __align__(16) bf16  sgz[CLEN][16];      // silu(z) (DMA)
    __shared__ __align__(16) float sdpT[16][TROW];     // [d][2i]=(dv), [2i+1]=(dv*xc)
    __shared__ __align__(16) float sbcT[16][TROW];     // [n][2i]=(B), [2i+1]=(C)
    __shared__ float2 ssk[CLEN][16];                   // (xc*Dskip, gz)
    __shared__ __align__(16) float sP[2][16][SPL];     // h*C staging, dbl-buffered

    auto stage = [&](int l0) {
        int s = tid, row = s >> 3, cc = s & 7;
        ld16((char*)&Adt[0][0] + (s & ~63) * 16,
             dtb + (size_t)(b * LL + l0 + row) * DTPAD + ((cc ^ (row & 7)) << 3));
        ld16((char*)&sbcraw[0][0] + (s & ~63) * 16,
             xdbl + (size_t)(b * LL + l0 + row) * NXP + DTRANK + cc * 4);
        s = tid + 256; row = s >> 3; cc = s & 7;
        ld16((char*)&Adt[0][0] + (s & ~63) * 16,
             dtb + (size_t)(b * LL + l0 + row) * DTPAD + ((cc ^ (row & 7)) << 3));
        ld16((char*)&sbcraw[0][0] + (s & ~63) * 16,
             xdbl + (size_t)(b * LL + l0 + row) * NXP + DTRANK + cc * 4);
        if (tid < 128) {
            int s2 = tid, r2 = s2 >> 1, c2 = s2 & 1;
            ld16((char*)&sxc[0][0] + (s2 & ~63) * 16,
                 xcb + (size_t)(b * LL + l0 + r2) * DI + d0 + c2 * 8);
        } else {
            int s2 = tid - 128, r2 = s2 >> 1, c2 = s2 & 1;
            ld16((char*)&sgz[0][0] + (s2 & ~63) * 16,
                 gzb + (size_t)(b * LL + l0 + r2) * DI + d0 + c2 * 8);
        }
    };

    // prologue: first chunk + persistent w_dt tile
    stage(0);
    if (tid < 128) {
        int r = tid >> 3, s2 = (tid & 7) * 8;
        *(bf16x8*)&Bdt[r][s2] = *(const bf16x8*)&wdt[(size_t)(d0 + r) * DTPAD + s2];
    }
    wait_vm0();
    __syncthreads();

    float h = 0.f;
    for (int c = 0; c < NC; ++c) {
        const int l0 = c * CLEN;
        // ---- delta tile via MFMA + softplus; pack transposed scan operands ----
        {
            floatx4 dacc = (floatx4){0.f, 0.f, 0.f, 0.f};
            const char* arow = (const char*)&Adt[16 * wv + lr][0];
            bf16x8 a0 = *(const bf16x8*)(arow + ((q ^ (lr & 7)) << 4));
            bf16x8 a1 = *(const bf16x8*)(arow + (((4 + q) ^ (lr & 7)) << 4));
            dacc = __builtin_amdgcn_mfma_f32_16x16x32_bf16(
                a0, *(const bf16x8*)&Bdt[lr][q * 8], dacc, 0, 0, 0);
            dacc = __builtin_amdgcn_mfma_f32_16x16x32_bf16(
                a1, *(const bf16x8*)&Bdt[lr][32 + q * 8], dacc, 0, 0, 0);
            float vv[4], xvv[4];
            #pragma unroll
            for (int r = 0; r < 4; ++r) {
                int l = 16 * wv + q * 4 + r;
                float v = dacc[r] + bi;
                v = (v > 20.f) ? v : log1pf(__expf(v));
                float xv = (float)sxc[l][lr];
                float gv = (float)sgz[l][lr];
                vv[r] = v; xvv[r] = xv;
                ssk[l][lr] = make_float2(xv * dsk, gv);
            }
            int L0 = 16 * wv + q * 4;
            *(float4*)&sdpT[lr][2 * L0] =
                make_float4(vv[0], vv[0] * xvv[0], vv[1], vv[1] * xvv[1]);
            *(float4*)&sdpT[lr][2 * L0 + 4] =
                make_float4(vv[2], vv[2] * xvv[2], vv[3], vv[3] * xvv[3]);
            #pragma unroll
            for (int k2 = 0; k2 < 4; ++k2) {
                int idx = tid + 256 * k2, ii = idx >> 4, dd2 = idx & 15;
                *(float2*)&sbcT[dd2][2 * ii] =
                    make_float2(sbcraw[ii][dd2], sbcraw[ii][16 + dd2]);
            }
        }
        __syncthreads();                    // (A) packed data visible; raw bufs consumed
        if (c + 1 < NC) stage(l0 + CLEN);   // async prefetch next chunk into raw bufs

        // scan group gS (16 steps) into sP[bufS]; all indices compile-time
        auto scan_group = [&](const int bufS, const int gS) {
            float4 d4[8], b4[8];
            const float4* dpr = (const float4*)&sdpT[dl][0];
            const float4* bcr = (const float4*)&sbcT[n][0];
            #pragma unroll
            for (int j = 0; j < 8; ++j) { d4[j] = dpr[gS * 8 + j]; b4[j] = bcr[gS * 8 + j]; }
            float* spw = &sP[bufS][0][dl * 17 + n];
            #pragma unroll
            for (int i = 0; i < 16; ++i) {
                float4 v = d4[i >> 1], w = b4[i >> 1];
                float dvx = (i & 1) ? v.z : v.x;
                float dpy = (i & 1) ? v.w : v.y;
                float bx  = (i & 1) ? w.z : w.x;
                float cy  = (i & 1) ? w.w : w.y;
                float e = exp2_raw(dvx * a2);
                h = __builtin_fmaf(e, h, dpy * bx);
                spw[i * SPL] = h * cy;
            }
        };
        // reduce group gR from sP[bufR]: y = sum_n, + skip/gate, store to global.
        // adjacent-pair tree == same association as the old DPP butterfly.
        auto red_group = [&](const int bufR, const int gR) {
            const float* rp = &sP[bufR][dl][n * 17];   // (dl,n) = (l-slot, d)
            float r[16];
            #pragma unroll
            for (int k = 0; k < 16; ++k) r[k] = rp[k];
            float s0 = r[0] + r[1],  s1 = r[2] + r[3];
            float s2 = r[4] + r[5],  s3 = r[6] + r[7];
            float s4 = r[8] + r[9],  s5 = r[10] + r[11];
            float s6 = r[12] + r[13], s7 = r[14] + r[15];
            float y = ((s0 + s1) + (s2 + s3)) + ((s4 + s5) + (s6 + s7));
            float2 sk = ssk[gR * 16 + dl][n];
            float yv = (y + sk.x) * sk.y;
            ybf[(size_t)(b * LL + l0 + gR * 16 + dl) * DI + d0 + n] = (bf16)yv;
        };

        scan_group(0, 0);
        __syncthreads();
        red_group(0, 0); scan_group(1, 1);
        __syncthreads();
        red_group(1, 1); scan_group(0, 2);
        __syncthreads();
        red_group(0, 2); scan_group(1, 3);
        __syncthreads();
        red_group(1, 3);
        wait_vm0();                         // staged(c+1) landed (covered by scan)
        __syncthreads();                    // safe to overwrite packed bufs next chunk
    }
}

// ---------------------------------------------------------------- head
__global__ __launch_bounds__(256) void head_norm_k(const float* __restrict__ x,
                                                   const float* __restrict__ fnw,
                                                   float* __restrict__ xn_buf) {
    int b = blockIdx.x;
    int tid = threadIdx.x;
    const float* xr = x + ((size_t)b * LL + (LL - 1)) * DD;
    __shared__ float sred[4];
    float v[3]; float ss = 0.f;
    for (int j = 0; j < 3; j++) { v[j] = xr[tid + j * 256]; ss += v[j] * v[j]; }
    for (int o = 1; o < 64; o <<= 1) ss += __shfl_xor(ss, o, 64);
    if ((tid & 63) == 0) sred[tid >> 6] = ss;
    __syncthreads();
    float scale = rsqrtf((sred[0] + sred[1] + sred[2] + sred[3]) / (float)DD + 1e-6f);
    for (int j = 0; j < 3; j++) {
        int c = tid + j * 256;
        xn_buf[(size_t)b * DD + c] = v[j] * scale * fnw[c];
    }
}

__global__ __launch_bounds__(256) void head_h1_k(const float* __restrict__ xn_buf,
                                                 const float* __restrict__ h1w,
                                                 const float* __restrict__ h1b,
                                                 float* __restrict__ h_buf) {
    int b  = blockIdx.x;
    int o0 = blockIdx.y * 64;
    int tid = threadIdx.x;
    __shared__ float sx[DD];
    for (int c = tid; c < DD; c += 256) sx[c] = xn_buf[(size_t)b * DD + c];
    __syncthreads();
    int wave = tid >> 6, lane = tid & 63;
    for (int j = 0; j < 16; j++) {
        int o = o0 + wave * 16 + j;
        const float* wrow = h1w + (size_t)o * DD;
        float acc = 0.f;
        for (int k = 0; k < 12; k++) {
            int c = lane + 64 * k;
            acc += wrow[c] * sx[c];
        }
        for (int off = 1; off < 64; off <<= 1) acc += __shfl_xor(acc, off, 64);
        if (lane == 0) h_buf[(size_t)b * DD + o] = acc + h1b[o];
    }
}

__global__ __launch_bounds__(256) void head_out_k(const float* __restrict__ h_buf,
                                                  const float* __restrict__ hnw,
                                                  const float* __restrict__ h2w,
                                                  const float* __restrict__ h2b,
                                                  float* __restrict__ out) {
    int b = blockIdx.x;
    int tid = threadIdx.x;
    __shared__ float hh[DD];
    __shared__ float sred[4];
    const float* hr = h_buf + (size_t)b * DD;
    float ss = 0.f;
    for (int c = tid; c < DD; c += 256) { float v = hr[c]; ss += v * v; }
    for (int o = 1; o < 64; o <<= 1) ss += __shfl_xor(ss, o, 64);
    if ((tid & 63) == 0) sred[tid >> 6] = ss;
    __syncthreads();
    float sc = rsqrtf((sred[0] + sred[1] + sred[2] + sred[3]) / (float)DD + 1e-6f);
    for (int c = tid; c < DD; c += 256) {
        float v = hr[c] * sc * hnw[c];
        hh[c] = 0.5f * v * (1.f + erff(v * 0.70710678118f));
    }
    __syncthreads();
    int w = tid >> 6, lane = tid & 63;
    for (int j = w; j < 10; j += 4) {
        float acc = 0.f;
        const float* wrow = h2w + (size_t)j * DD;
        for (int c = lane; c < DD; c += 64) acc += hh[c] * wrow[c];
        for (int o = 1; o < 64; o <<= 1) acc += __shfl_xor(acc, o, 64);
        if (lane == 0) out[b * 10 + j] = acc + h2b[j];
    }
}

// ----------------------------------------------------------------
extern "C" void kernel_launch(void* const* d_in, const int* in_sizes, int n_in,
                              void* d_out, int out_size, void* d_ws, size_t ws_size,
                              hipStream_t stream) {
    const float* x_in      = (const float*)d_in[0];
    const float* norm_w    = (const float*)d_in[1];
    const float* in_proj_w = (const float*)d_in[2];
    const float* conv_w    = (const float*)d_in[3];
    const float* conv_b    = (const float*)d_in[4];
    const float* x_proj_w  = (const float*)d_in[5];
    const float* dt_proj_w = (const float*)d_in[6];
    const float* dt_proj_b = (const float*)d_in[7];
    const float* A_log     = (const float*)d_in[8];
    const float* D_skip    = (const float*)d_in[9];
    const float* out_proj_w= (const float*)d_in[10];
    const float* fnw       = (const float*)d_in[11];
    const float* h1w       = (const float*)d_in[12];
    const float* h1b       = (const float*)d_in[13];
    const float* hnw       = (const float*)d_in[14];
    const float* h2w       = (const float*)d_in[15];
    const float* h2b       = (const float*)d_in[16];
    float* out = (float*)d_out;

    char* ws = (char*)d_ws;
    size_t off = 0;
    auto alloc = [&](size_t bytes) -> void* {
        void* p = ws + off;
        off += (bytes + 255) & ~(size_t)255;
        return p;
    };
    bf16* w_in  = (bf16*)alloc((size_t)N1 * 2);
    bf16* w_xp  = (bf16*)alloc((size_t)N2 * 2);
    bf16* w_dt  = (bf16*)alloc((size_t)N3 * 2);
    bf16* w_out = (bf16*)alloc((size_t)N4 * 2);
    bf16* xn_bf = (bf16*)alloc((size_t)MROWS * DD * 2);
    bf16* xz_bf = (bf16*)alloc((size_t)MROWS * 2 * DI * 2);
    bf16* xc_bf = (bf16*)alloc((size_t)MROWS * DI * 2);
    bf16* gz_bf = (bf16*)alloc((size_t)MROWS * DI * 2);
    float* xdbl = (float*)alloc((size_t)MROWS * NXP * 4);
    bf16* dt_bf = (bf16*)alloc((size_t)MROWS * DTPAD * 2);
    bf16* y_bf  = (bf16*)alloc((size_t)MROWS * DI * 2);
    float* x_buf= (float*)alloc((size_t)MROWS * DD * 4);
    float* xnl  = (float*)alloc((size_t)BB * DD * 4);
    float* hbuf = (float*)alloc((size_t)BB * DD * 4);
    float* xp_part = (float*)alloc((size_t)KSPLIT * MROWS * NXP * 4);
    float* op_part = (float*)alloc((size_t)OPKS * MROWS * DD * 4);

    // all weight conversions in one launch
    {
        int ntot = N1 + N2 + N3 + N4;
        cvt_all_k<<<(ntot + 255) / 256, 256, 0, stream>>>(
            in_proj_w, x_proj_w, dt_proj_w, out_proj_w, w_in, w_xp, w_dt, w_out);
    }

    for (int i = 0; i < 4; i++) {
        const float* x_src = (i == 0) ? x_in : x_buf;
        // 1. rmsnorm (layer 0 only; later layers get xn_bf from fused op_reduce_norm)
        if (i == 0)
            rmsnorm_k<<<MROWS, 256, 0, stream>>>(x_src, norm_w, xn_bf);
        // 2. in_proj: (2048 x 3072), bf16 out
        gemm_bt<1><<<dim3(MROWS / 128, 3072 / 128), 256, 0, stream>>>(
            xn_bf, w_in + (size_t)i * 3072 * 768, nullptr, xz_bf,
            MROWS, 2 * DI, DD);
        // 3. causal conv + silu + silu(z) gate (bf16 outputs)
        conv_silu_k<<<(MROWS * (DI / 4) + 255) / 256, 256, 0, stream>>>(
            xz_bf, conv_w + (size_t)i * DI * 4, conv_b + (size_t)i * DI, xc_bf, gz_bf);
        // 4. x_proj split-K + reduce -> xdbl f32 + padded bf16 dt
        gemm_xp<<<dim3(MROWS / 64, KSPLIT), 256, 0, stream>>>(
            xc_bf, w_xp + (size_t)i * NXP * DI, xp_part);
        xp_reduce_k<<<(MROWS * NXP + 255) / 256, 256, 0, stream>>>(xp_part, xdbl, dt_bf);
        // 5. single-pass sequential scan (dt_proj fused, D-skip + gate fused) -> y bf16
        scan_k<<<dim3(DI / 16, BB), 256, 0, stream>>>(
            dt_bf, w_dt + (size_t)i * DI * DTPAD, dt_proj_b + (size_t)i * DI,
            xc_bf, gz_bf, xdbl, A_log + (size_t)i * DI * DSTATE,
            D_skip + (size_t)i * DI, y_bf);
        // 6. out_proj split-K -> partials; fused reduce + residual + next rmsnorm
        gemm_bt<5><<<dim3(MROWS / 128, DD / 128, OPKS), 256, 0, stream>>>(
            y_bf, w_out + (size_t)i * DD * DI, op_part, nullptr,
            MROWS, DD, DI);
        op_reduce_norm_k<<<MROWS, 256, 0, stream>>>(
            op_part, x_src, norm_w + ((i + 1) & 3) * DD, x_buf, xn_bf);
    }

    head_norm_k<<<BB, 256, 0, stream>>>(x_buf, fnw, xnl);
    head_h1_k<<<dim3(BB, DD / 64), 256, 0, stream>>>(xnl, h1w, h1b, hbuf);
    head_out_k<<<BB, 256, 0, stream>>>(hbuf, hnw, h2w, h2b, out);
}

// Round 4
// 658.536 us; speedup vs baseline: 1.0873x; 1.0873x over previous
//
#include <hip/hip_runtime.h>
#include <hip/hip_bf16.h>
#include <math.h>

typedef __bf16 bf16;
typedef __bf16 bf16x4 __attribute__((ext_vector_type(4)));
typedef __bf16 bf16x8 __attribute__((ext_vector_type(8)));
typedef float floatx4 __attribute__((ext_vector_type(4)));

#define BB 2
#define LL 1024
#define DD 768
#define DI 1536
#define MROWS 2048   // B*L
#define NXP 80       // dt_rank + 2*d_state
#define DTRANK 48
#define DTPAD 64     // dt K padded to 64
#define DSTATE 16
#define NC 16        // scan chunks
#define CLEN 64      // scan chunk length (NC*CLEN == LL)
#define KSPLIT 16    // x_proj split-K factor (K-seg = 96)
#define OPKS 4       // out_proj split-K factor (K-seg = 384)
#define LOG2E 1.4426950408889634f
#define TROW 132     // floats per sdpT/sbcT row (128 data + 4 pad)
#define SYROW 68     // floats per syT row

// async global->LDS, 16 B per lane; lds dest must be wave-uniform base (+lane*16)
__device__ __forceinline__ void ld16(void* lds, const void* g) {
    __builtin_amdgcn_global_load_lds(
        (const __attribute__((address_space(1))) void*)g,
        (__attribute__((address_space(3))) void*)lds, 16, 0, 0);
}

// drain this wave's outstanding async global_load_lds before signalling barrier.
__device__ __forceinline__ void wait_vm0() {
    asm volatile("s_waitcnt vmcnt(0)" ::: "memory");
}

// DPP row-reduce over 16 lanes (one DPP row): lane 0 of each row gets the sum.
__device__ __forceinline__ float row16_sum(float x) {
    float t;
    t = __int_as_float(__builtin_amdgcn_update_dpp(0, __float_as_int(x), 0x111, 0xF, 0xF, true)); x += t;
    t = __int_as_float(__builtin_amdgcn_update_dpp(0, __float_as_int(x), 0x112, 0xF, 0xF, true)); x += t;
    t = __int_as_float(__builtin_amdgcn_update_dpp(0, __float_as_int(x), 0x114, 0xF, 0xF, true)); x += t;
    t = __int_as_float(__builtin_amdgcn_update_dpp(0, __float_as_int(x), 0x118, 0xF, 0xF, true)); x += t;
    return x;
}

// raw v_exp_f32 (no ocml denormal fixup; exp2(x<-126) flushes to 0 which is fine here)
__device__ __forceinline__ float exp2_raw(float x) {
#if __has_builtin(__builtin_amdgcn_exp2f)
    return __builtin_amdgcn_exp2f(x);
#else
    float r; asm("v_exp_f32 %0, %1" : "=v"(r) : "v"(x)); return r;
#endif
}

// ---------------------------------------------------------------- all weight cvt in one kernel
#define N1 (4 * 3072 * 768)
#define N2 (4 * NXP * DI)
#define N3 (4 * DI * DTPAD)
#define N4 (4 * DD * DI)
__global__ __launch_bounds__(256) void cvt_all_k(const float* __restrict__ in_proj_w,
                                                 const float* __restrict__ x_proj_w,
                                                 const float* __restrict__ dt_proj_w,
                                                 const float* __restrict__ out_proj_w,
                                                 bf16* __restrict__ w_in,
                                                 bf16* __restrict__ w_xp,
                                                 bf16* __restrict__ w_dt,
                                                 bf16* __restrict__ w_out) {
    int i = blockIdx.x * 256 + threadIdx.x;
    if (i < N1) { w_in[i] = (bf16)in_proj_w[i]; return; }
    i -= N1;
    if (i < N2) { w_xp[i] = (bf16)x_proj_w[i]; return; }
    i -= N2;
    if (i < N3) {
        int row = i >> 6, c = i & 63;
        w_dt[i] = (c < DTRANK) ? (bf16)dt_proj_w[row * DTRANK + c] : (bf16)0.f;
        return;
    }
    i -= N3;
    if (i < N4) w_out[i] = (bf16)out_proj_w[i];
}

// ---------------------------------------------------------------- rmsnorm -> bf16 (layer 0 only)
__global__ __launch_bounds__(256) void rmsnorm_k(const float* __restrict__ x,
                                                 const float* __restrict__ w,
                                                 bf16* __restrict__ out) {
    int row = blockIdx.x;
    const float* xr = x + (size_t)row * DD;
    int tid = threadIdx.x;
    float v[3]; float ss = 0.f;
    for (int j = 0; j < 3; j++) { v[j] = xr[tid + j * 256]; ss += v[j] * v[j]; }
    for (int o = 1; o < 64; o <<= 1) ss += __shfl_xor(ss, o, 64);
    __shared__ float sred[4];
    if ((tid & 63) == 0) sred[tid >> 6] = ss;
    __syncthreads();
    float scale = rsqrtf((sred[0] + sred[1] + sred[2] + sred[3]) / (float)DD + 1e-6f);
    for (int j = 0; j < 3; j++) {
        int c = tid + j * 256;
        out[(size_t)row * DD + c] = (bf16)(v[j] * scale * w[c]);
    }
}

// ---------------------------------------------------------------- GEMM: C = A @ W^T
// MODE 1: store bf16 | MODE 5: split-K partials f32
template <int MODE>
__global__ __launch_bounds__(256) void gemm_bt(const bf16* __restrict__ A,
                                               const bf16* __restrict__ W,
                                               float* __restrict__ Cf,
                                               bf16* __restrict__ Cb,
                                               int M, int N, int K) {
    __shared__ bf16 As[128][32];
    __shared__ bf16 Ws[128][32];
    const int tid  = threadIdx.x;
    const int m0   = blockIdx.x * 128;
    const int n0   = blockIdx.y * 128;
    const int wave = tid >> 6;
    const int lane = tid & 63;
    const int wm   = (wave >> 1) * 64;
    const int wn   = (wave & 1) * 64;
    const int lrow = lane & 15;
    const int quad = lane >> 4;

    int kbeg = 0, kend = K;
    if constexpr (MODE == 5) {
        int kseg = K / gridDim.z;
        kbeg = blockIdx.z * kseg;
        kend = kbeg + kseg;
        Cf  += (size_t)blockIdx.z * M * N;
    }

    floatx4 acc[4][4];
    for (int mi = 0; mi < 4; mi++)
        for (int ni = 0; ni < 4; ni++) acc[mi][ni] = (floatx4){0.f, 0.f, 0.f, 0.f};

    const int r0  = tid >> 2;        // 0..63
    const int r1  = r0 + 64;         // 64..127
    const int seg = (tid & 3) * 8;   // 0,8,16,24
    char* asb0 = (char*)As + wave * 1024;
    char* asb1 = (char*)As + 4096 + wave * 1024;
    char* wsb0 = (char*)Ws + wave * 1024;
    char* wsb1 = (char*)Ws + 4096 + wave * 1024;

    for (int kb = kbeg; kb < kend; kb += 32) {
        int gk = kb + seg;
        __syncthreads();   // previous iteration's LDS reads done
        ld16(asb0, A + (size_t)(m0 + r0) * K + gk);
        ld16(asb1, A + (size_t)(m0 + r1) * K + gk);
        ld16(wsb0, W + (size_t)(n0 + r0) * K + gk);
        ld16(wsb1, W + (size_t)(n0 + r1) * K + gk);
        wait_vm0();        // this wave's async LDS fills landed
        __syncthreads();   // all waves' fills landed -> tiles ready
        bf16x8 af[4], wf[4];
        for (int mi = 0; mi < 4; mi++) af[mi] = *(const bf16x8*)&As[wm + mi * 16 + lrow][quad * 8];
        for (int ni = 0; ni < 4; ni++) wf[ni] = *(const bf16x8*)&Ws[wn + ni * 16 + lrow][quad * 8];
        for (int mi = 0; mi < 4; mi++)
            for (int ni = 0; ni < 4; ni++)
                acc[mi][ni] = __builtin_amdgcn_mfma_f32_16x16x32_bf16(af[mi], wf[ni], acc[mi][ni], 0, 0, 0);
    }
    for (int mi = 0; mi < 4; mi++) {
        int rowb = m0 + wm + mi * 16 + quad * 4;
        for (int ni = 0; ni < 4; ni++) {
            int col = n0 + wn + ni * 16 + lrow;
            for (int r = 0; r < 4; r++) {
                int row = rowb + r;
                float v = acc[mi][ni][r];
                if constexpr (MODE == 1) Cb[(size_t)row * N + col] = (bf16)v;
                else                     Cf[(size_t)row * N + col] = v;
            }
        }
    }
}

// ---------------------------------------------------------------- out_proj partials + residual + NEXT layer rmsnorm (fused)
__global__ __launch_bounds__(256) void op_reduce_norm_k(const float* __restrict__ part,
                                                        const float* __restrict__ resid,
                                                        const float* __restrict__ nw,
                                                        float* __restrict__ xout,
                                                        bf16* __restrict__ xnb) {
    int row = blockIdx.x;
    int tid = threadIdx.x;
    float v[3]; float ss = 0.f;
    for (int j = 0; j < 3; j++) {
        int c = tid + j * 256;
        size_t idx = (size_t)row * DD + c;
        float s = resid[idx];
        for (int ks = 0; ks < OPKS; ks++) s += part[(size_t)ks * MROWS * DD + idx];
        v[j] = s;
        xout[idx] = s;
        ss += s * s;
    }
    for (int o = 1; o < 64; o <<= 1) ss += __shfl_xor(ss, o, 64);
    __shared__ float sred[4];
    if ((tid & 63) == 0) sred[tid >> 6] = ss;
    __syncthreads();
    float scale = rsqrtf((sred[0] + sred[1] + sred[2] + sred[3]) / (float)DD + 1e-6f);
    for (int j = 0; j < 3; j++) {
        int c = tid + j * 256;
        xnb[(size_t)row * DD + c] = (bf16)(v[j] * scale * nw[c]);
    }
}

// ---------------------------------------------------------------- x_proj split-K GEMM
__global__ __launch_bounds__(256) void gemm_xp(const bf16* __restrict__ A,
                                               const bf16* __restrict__ W,
                                               float* __restrict__ part) {
    __shared__ bf16 As[64][40];
    __shared__ bf16 Ws[128][40];
    const int tid  = threadIdx.x;
    const int m0   = blockIdx.x * 64;
    const int ks   = blockIdx.y;
    const int k0   = ks * (DI / KSPLIT);
    const int wave = tid >> 6;
    const int lane = tid & 63;
    const int lrow = lane & 15;
    const int quad = lane >> 4;
    const int wm   = wave * 16;

    floatx4 acc[5];
    for (int ni = 0; ni < 5; ni++) acc[ni] = (floatx4){0.f, 0.f, 0.f, 0.f};

    const int ra  = tid >> 2;
    const int rw1 = ra + 64;
    const int seg = (tid & 3) * 8;

    for (int kb = 0; kb < DI / KSPLIT; kb += 32) {
        int gk = k0 + kb + seg;
        bf16x8 va = *(const bf16x8*)(A + (size_t)(m0 + ra) * DI + gk);
        bf16x8 vw0, vw1;
        if (ra < NXP) vw0 = *(const bf16x8*)(W + (size_t)ra * DI + gk);
        else          for (int j = 0; j < 8; j++) vw0[j] = (bf16)0.f;
        if (rw1 < NXP) vw1 = *(const bf16x8*)(W + (size_t)rw1 * DI + gk);
        else           for (int j = 0; j < 8; j++) vw1[j] = (bf16)0.f;
        __syncthreads();
        *(bf16x8*)&As[ra][seg]  = va;
        *(bf16x8*)&Ws[ra][seg]  = vw0;
        *(bf16x8*)&Ws[rw1][seg] = vw1;
        __syncthreads();
        bf16x8 af = *(const bf16x8*)&As[wm + lrow][quad * 8];
        for (int ni = 0; ni < 5; ni++) {
            bf16x8 wf = *(const bf16x8*)&Ws[ni * 16 + lrow][quad * 8];
            acc[ni] = __builtin_amdgcn_mfma_f32_16x16x32_bf16(af, wf, acc[ni], 0, 0, 0);
        }
    }
    float* pout = part + (size_t)ks * MROWS * NXP;
    for (int ni = 0; ni < 5; ni++) {
        int col = ni * 16 + lrow;
        for (int r = 0; r < 4; r++) {
            int row = m0 + wm + quad * 4 + r;
            pout[(size_t)row * NXP + col] = acc[ni][r];
        }
    }
}

// reduce split-K partials -> xdbl f32 + padded bf16 dt
__global__ __launch_bounds__(256) void xp_reduce_k(const float* __restrict__ part,
                                                   float* __restrict__ xdbl,
                                                   bf16* __restrict__ dtbf) {
    int idx = blockIdx.x * 256 + threadIdx.x;
    if (idx >= MROWS * NXP) return;
    float s = 0.f;
    for (int j = 0; j < KSPLIT; j++) s += part[(size_t)j * MROWS * NXP + idx];
    xdbl[idx] = s;
    int m = idx / NXP, c = idx - m * NXP;
    if (c < DTRANK)      dtbf[m * DTPAD + c] = (bf16)s;
    else if (c < DTPAD)  dtbf[m * DTPAD + c] = (bf16)0.f;
}

// ---------------------------------------------------------------- causal depthwise conv + silu + gate (4-wide, bf16 outputs)
__global__ __launch_bounds__(256) void conv_silu_k(const bf16* __restrict__ xz,
                                                   const float* __restrict__ cw,
                                                   const float* __restrict__ cb,
                                                   bf16* __restrict__ xcb,
                                                   bf16* __restrict__ gzb) {
    int t = blockIdx.x * 256 + threadIdx.x;
    if (t >= MROWS * (DI / 4)) return;
    int m = t / (DI / 4);
    int d = (t - m * (DI / 4)) * 4;
    int l = m & (LL - 1);
    float acc[4];
    floatx4 cwv[4];
    for (int q = 0; q < 4; q++) {
        acc[q] = cb[d + q];
        cwv[q] = *(const floatx4*)&cw[(d + q) * 4];
    }
    for (int k = 0; k < 4; k++) {
        int lp = l - 3 + k;
        if (lp >= 0) {
            bf16x4 v = *(const bf16x4*)&xz[(size_t)(m - 3 + k) * (2 * DI) + d];
            for (int q = 0; q < 4; q++) acc[q] += (float)v[q] * cwv[q][k];
        }
    }
    bf16x4 xo, go;
    bf16x4 z4 = *(const bf16x4*)&xz[(size_t)m * (2 * DI) + DI + d];
    for (int q = 0; q < 4; q++) {
        float s = acc[q] / (1.f + __expf(-acc[q]));
        xo[q] = (bf16)s;
        float zv = (float)z4[q];
        go[q] = (bf16)(zv / (1.f + __expf(-zv)));
    }
    *(bf16x4*)&xcb[(size_t)m * DI + d] = xo;
    *(bf16x4*)&gzb[(size_t)m * DI + d] = go;
}

// ---------------------------------------------------------------- chunk-parallel 2-phase selective scan (v4)
// R3 post-mortem: single-pass = 0.75 waves/SIMD structural cap -> 65% stall no
// matter the inner loop. Revert to R0's chunk-parallel structure (3072 blocks,
// ~13 waves/CU, VALUBusy 85%) but with v2's cheap inner loop (transposed
// operands, float4 register prefetch, ~2x fewer issue slots/iter than R0) and
// a dedicated tiny compose kernel (removes 15 dependent global loads per
// scan2 block).
// Phase 1: chunk-local scan from h=0 -> (P, S) = (exp2(a2*sum dv), h_local).
__global__ __launch_bounds__(256) void scan1_k(const bf16* __restrict__ dtb,
                                               const bf16* __restrict__ wdt,
                                               const float* __restrict__ dtbias,
                                               const bf16* __restrict__ xcb,
                                               const float* __restrict__ xdbl,
                                               const float* __restrict__ A_log,
                                               float* __restrict__ Pbuf,
                                               float* __restrict__ Sbuf) {
    const int b   = blockIdx.y;
    const int d0  = blockIdx.x * 16;
    const int c   = blockIdx.z;
    const int tid = threadIdx.x;
    const int dl  = tid >> 4;
    const int n   = tid & 15;
    const int wv  = tid >> 6;
    const int lane = tid & 63;
    const int lr  = lane & 15;
    const int q   = lane >> 4;
    const int l0  = c * CLEN;

    const float a2 = -__expf(A_log[(size_t)(d0 + dl) * DSTATE + n]) * LOG2E;
    const float bi = dtbias[d0 + lr];

    __shared__ __align__(16) bf16  Bdt[16][72];
    __shared__ __align__(16) bf16  Adt[CLEN][64];   // dt rows, XOR-swizzled cols (DMA)
    __shared__ __align__(16) float sbraw[CLEN][16]; // raw B (DMA)
    __shared__ __align__(16) bf16  sxc[CLEN][16];   // conv out (DMA)
    __shared__ __align__(16) float sdpT[16][TROW];  // [d][2i]=(dv), [2i+1]=(dv*xc)
    __shared__ __align__(16) float sbT[16][68];     // [n][i]=B

    {   // stage (all DMA except padded Bdt)
        int s = tid, row = s >> 3, cc = s & 7;
        ld16((char*)&Adt[0][0] + (s & ~63) * 16,
             dtb + (size_t)(b * LL + l0 + row) * DTPAD + ((cc ^ (row & 7)) << 3));
        s = tid + 256; row = s >> 3; cc = s & 7;
        ld16((char*)&Adt[0][0] + (s & ~63) * 16,
             dtb + (size_t)(b * LL + l0 + row) * DTPAD + ((cc ^ (row & 7)) << 3));
        {
            int r2 = tid >> 2, c2 = tid & 3;
            ld16((char*)&sbraw[0][0] + (tid & ~63) * 16,
                 xdbl + (size_t)(b * LL + l0 + r2) * NXP + DTRANK + c2 * 4);
        }
        if (tid < 128) {
            int r2 = tid >> 1, c2 = tid & 1;
            ld16((char*)&sxc[0][0] + (tid & ~63) * 16,
                 xcb + (size_t)(b * LL + l0 + r2) * DI + d0 + c2 * 8);
            int r = tid >> 3, s2 = (tid & 7) * 8;
            *(bf16x8*)&Bdt[r][s2] = *(const bf16x8*)&wdt[(size_t)(d0 + r) * DTPAD + s2];
        }
    }
    wait_vm0();
    __syncthreads();

    {   // delta tile via MFMA + softplus; pack transposed operands
        floatx4 dacc = (floatx4){0.f, 0.f, 0.f, 0.f};
        const char* arow = (const char*)&Adt[16 * wv + lr][0];
        bf16x8 a0 = *(const bf16x8*)(arow + ((q ^ (lr & 7)) << 4));
        bf16x8 a1 = *(const bf16x8*)(arow + (((4 + q) ^ (lr & 7)) << 4));
        dacc = __builtin_amdgcn_mfma_f32_16x16x32_bf16(
            a0, *(const bf16x8*)&Bdt[lr][q * 8], dacc, 0, 0, 0);
        dacc = __builtin_amdgcn_mfma_f32_16x16x32_bf16(
            a1, *(const bf16x8*)&Bdt[lr][32 + q * 8], dacc, 0, 0, 0);
        float vv[4], xvv[4];
        #pragma unroll
        for (int r = 0; r < 4; ++r) {
            int l = 16 * wv + q * 4 + r;
            float v = dacc[r] + bi;
            v = (v > 20.f) ? v : log1pf(__expf(v));
            vv[r] = v; xvv[r] = (float)sxc[l][lr];
        }
        int L0 = 16 * wv + q * 4;
        *(float4*)&sdpT[lr][2 * L0] =
            make_float4(vv[0], vv[0] * xvv[0], vv[1], vv[1] * xvv[1]);
        *(float4*)&sdpT[lr][2 * L0 + 4] =
            make_float4(vv[2], vv[2] * xvv[2], vv[3], vv[3] * xvv[3]);
        #pragma unroll
        for (int k2 = 0; k2 < 4; ++k2) {
            int idx = tid + 256 * k2, ii = idx >> 4, dd2 = idx & 15;
            sbT[dd2][ii] = sbraw[ii][dd2];
        }
    }
    __syncthreads();

    // 64-step local scan, register double-buffered float4 prefetch
    float h = 0.f, sd = 0.f;
    {
        const float4* dpr = (const float4*)&sdpT[dl][0];
        const float4* bpr = (const float4*)&sbT[n][0];
        float4 dA[4], dB2[4], bA[2], bB2[2];
        #pragma unroll
        for (int t = 0; t < 4; ++t) dA[t] = dpr[t];
        #pragma unroll
        for (int t = 0; t < 2; ++t) bA[t] = bpr[t];
        #pragma unroll
        for (int g = 0; g < 8; ++g) {
            if (g + 1 < 8) {
                #pragma unroll
                for (int t = 0; t < 4; ++t) {
                    if ((g & 1) == 0) dB2[t] = dpr[(g + 1) * 4 + t];
                    else              dA[t]  = dpr[(g + 1) * 4 + t];
                }
                #pragma unroll
                for (int t = 0; t < 2; ++t) {
                    if ((g & 1) == 0) bB2[t] = bpr[(g + 1) * 2 + t];
                    else              bA[t]  = bpr[(g + 1) * 2 + t];
                }
            }
            #pragma unroll
            for (int i = 0; i < 8; ++i) {
                float4 v = ((g & 1) == 0) ? dA[i >> 1] : dB2[i >> 1];
                float4 w = ((g & 1) == 0) ? bA[i >> 2] : bB2[i >> 2];
                float dvx = (i & 1) ? v.z : v.x;
                float dpy = (i & 1) ? v.w : v.y;
                float bx  = ((i & 3) == 0) ? w.x : ((i & 3) == 1) ? w.y
                          : ((i & 3) == 2) ? w.z : w.w;
                float e = exp2_raw(dvx * a2);
                h = __builtin_fmaf(e, h, dpy * bx);
                sd += dvx;
            }
        }
    }
    size_t o = (((size_t)c * BB + b) * DI + (d0 + dl)) * DSTATE + n;
    Pbuf[o] = exp2_raw(a2 * sd);
    Sbuf[o] = h;
}

// Prefix-compose (P,S) over chunks -> H0[c] = h entering chunk c.
__global__ __launch_bounds__(256) void compose_k(const float* __restrict__ P,
                                                 const float* __restrict__ S,
                                                 float* __restrict__ H0) {
    int idx = blockIdx.x * 256 + threadIdx.x;   // over BB*DI*DSTATE
    const size_t stride = (size_t)BB * DI * DSTATE;
    float h = 0.f;
    #pragma unroll
    for (int c = 0; c < NC; ++c) {
        H0[(size_t)c * stride + idx] = h;
        h = __builtin_fmaf(P[(size_t)c * stride + idx], h, S[(size_t)c * stride + idx]);
    }
}

// Phase 2: re-run local scan from H0, emit y (D-skip + gate fused).
// LDS overlay: syT aliases the dead (Adt|sbcraw) staging region -> 39.7 KB
// total -> 4 blocks/CU (was 3 at 52 KB).
__global__ __launch_bounds__(256) void scan2_k(const bf16* __restrict__ dtb,
                                               const bf16* __restrict__ wdt,
                                               const float* __restrict__ dtbias,
                                               const bf16* __restrict__ xcb,
                                               const bf16* __restrict__ gzb,
                                               const float* __restrict__ xdbl,
                                               const float* __restrict__ A_log,
                                               const float* __restrict__ Dskip,
                                               const float* __restrict__ H0buf,
                                               bf16* __restrict__ ybf) {
    const int b   = blockIdx.y;
    const int d0  = blockIdx.x * 16;
    const int c   = blockIdx.z;
    const int tid = threadIdx.x;
    const int dl  = tid >> 4;
    const int n   = tid & 15;
    const int wv  = tid >> 6;
    const int lane = tid & 63;
    const int lr  = lane & 15;
    const int q   = lane >> 4;
    const int l0  = c * CLEN;

    const float a2 = -__expf(A_log[(size_t)(d0 + dl) * DSTATE + n]) * LOG2E;
    const float bi = dtbias[d0 + lr];

    __shared__ __align__(16) bf16  Bdt[16][72];
    __shared__ __align__(16) bf16  sxc[CLEN][16];
    __shared__ __align__(16) bf16  sgz[CLEN][16];
    __shared__ __align__(16) float sdpT[16][TROW];
    __shared__ __align__(16) float sbcT[16][TROW];
    __shared__ __align__(16) char  sov[16384];   // Adt(8K)+sbcraw(8K) -> later syT
    bf16  (*Adt)[64]     = (bf16 (*)[64])sov;
    float (*sbcraw)[32]  = (float (*)[32])(sov + 8192);
    float (*syT)[SYROW]  = (float (*)[SYROW])sov;

    // h entering this chunk (from compose)
    float h = H0buf[((size_t)c * BB + b) * (DI * DSTATE) + (size_t)(d0 + dl) * DSTATE + n];

    {   // stage
        int s = tid, row = s >> 3, cc = s & 7;
        ld16((char*)&Adt[0][0] + (s & ~63) * 16,
             dtb + (size_t)(b * LL + l0 + row) * DTPAD + ((cc ^ (row & 7)) << 3));
        ld16((char*)&sbcraw[0][0] + (s & ~63) * 16,
             xdbl + (size_t)(b * LL + l0 + row) * NXP + DTRANK + cc * 4);
        s = tid + 256; row = s >> 3; cc = s & 7;
        ld16((char*)&Adt[0][0] + (s & ~63) * 16,
             dtb + (size_t)(b * LL + l0 + row) * DTPAD + ((cc ^ (row & 7)) << 3));
        ld16((char*)&sbcraw[0][0] + (s & ~63) * 16,
             xdbl + (size_t)(b * LL + l0 + row) * NXP + DTRANK + cc * 4);
        if (tid < 128) {
            int r2 = tid >> 1, c2 = tid & 1;
            ld16((char*)&sxc[0][0] + (tid & ~63) * 16,
                 xcb + (size_t)(b * LL + l0 + r2) * DI + d0 + c2 * 8);
            int r = tid >> 3, s2 = (tid & 7) * 8;
            *(bf16x8*)&Bdt[r][s2] = *(const bf16x8*)&wdt[(size_t)(d0 + r) * DTPAD + s2];
        } else {
            int t2 = tid - 128, r2 = t2 >> 1, c2 = t2 & 1;
            ld16((char*)&sgz[0][0] + (t2 & ~63) * 16,
                 gzb + (size_t)(b * LL + l0 + r2) * DI + d0 + c2 * 8);
        }
    }
    wait_vm0();
    __syncthreads();

    {   // delta tile via MFMA + softplus; pack transposed scan operands
        floatx4 dacc = (floatx4){0.f, 0.f, 0.f, 0.f};
        const char* arow = (const char*)&Adt[16 * wv + lr][0];
        bf16x8 a0 = *(const bf16x8*)(arow + ((q ^ (lr & 7)) << 4));
        bf16x8 a1 = *(const bf16x8*)(arow + (((4 + q) ^ (lr & 7)) << 4));
        dacc = __builtin_amdgcn_mfma_f32_16x16x32_bf16(
            a0, *(const bf16x8*)&Bdt[lr][q * 8], dacc, 0, 0, 0);
        dacc = __builtin_amdgcn_mfma_f32_16x16x32_bf16(
            a1, *(const bf16x8*)&Bdt[lr][32 + q * 8], dacc, 0, 0, 0);
        float vv[4], xvv[4];
        #pragma unroll
        for (int r = 0; r < 4; ++r) {
            int l = 16 * wv + q * 4 + r;
            float v = dacc[r] + bi;
            v = (v > 20.f) ? v : log1pf(__expf(v));
            vv[r] = v; xvv[r] = (float)sxc[l][lr];
        }
        int L0 = 16 * wv + q * 4;
        *(float4*)&sdpT[lr][2 * L0] =
            make_float4(vv[0], vv[0] * xvv[0], vv[1], vv[1] * xvv[1]);
        *(float4*)&sdpT[lr][2 * L0 + 4] =
            make_float4(vv[2], vv[2] * xvv[2], vv[3], vv[3] * xvv[3]);
        #pragma unroll
        for (int k2 = 0; k2 < 4; ++k2) {
            int idx = tid + 256 * k2, ii = idx >> 4, dd2 = idx & 15;
            *(float2*)&sbcT[dd2][2 * ii] =
                make_float2(sbcraw[ii][dd2], sbcraw[ii][16 + dd2]);
        }
    }
    __syncthreads();   // pack done; Adt/sbcraw dead -> region becomes syT

    {   // 64-step scan: 8 groups of 8, register double-buffered prefetch
        const float4* dpr = (const float4*)&sdpT[dl][0];
        const float4* bcr = (const float4*)&sbcT[n][0];
        float4 dA[4], bA[4], dB2[4], bB2[4];
        float y4[4];
        #pragma unroll
        for (int t = 0; t < 4; ++t) { dA[t] = dpr[t]; bA[t] = bcr[t]; }
        #pragma unroll
        for (int g = 0; g < 8; ++g) {
            #pragma unroll
            for (int t = 0; t < 4; ++t) {
                if (g + 1 < 8) {
                    if ((g & 1) == 0) { dB2[t] = dpr[(g + 1) * 4 + t]; bB2[t] = bcr[(g + 1) * 4 + t]; }
                    else              { dA[t]  = dpr[(g + 1) * 4 + t]; bA[t]  = bcr[(g + 1) * 4 + t]; }
                }
            }
            #pragma unroll
            for (int i = 0; i < 8; ++i) {
                float4 v = ((g & 1) == 0) ? dA[i >> 1] : dB2[i >> 1];
                float4 w = ((g & 1) == 0) ? bA[i >> 1] : bB2[i >> 1];
                float dvx = (i & 1) ? v.z : v.x;
                float dpy = (i & 1) ? v.w : v.y;
                float bx  = (i & 1) ? w.z : w.x;
                float cy  = (i & 1) ? w.w : w.y;
                float e = exp2_raw(dvx * a2);
                h = __builtin_fmaf(e, h, dpy * bx);
                y4[i & 3] = row16_sum(h * cy);
                if ((i & 3) == 3 && n == 0) {
                    *(floatx4*)&syT[dl][g * 8 + i - 3] =
                        (floatx4){y4[0], y4[1], y4[2], y4[3]};
                }
            }
        }
    }
    __syncthreads();   // syT visible

    // emit: (y + xc*D) * silu(z); xc/gz straight from staged tiles
    #pragma unroll
    for (int k2 = 0; k2 < 4; ++k2) {
        int idx = tid + 256 * k2, ii = idx >> 4, dd = idx & 15;
        float xv = (float)sxc[ii][dd];
        float gv = (float)sgz[ii][dd];
        float yv = (syT[dd][ii] + xv * Dskip[d0 + dd]) * gv;
        ybf[(size_t)(b * LL + l0 + ii) * DI + d0 + dd] = (bf16)yv;
    }
}

// ---------------------------------------------------------------- head
__global__ __launch_bounds__(256) void head_norm_k(const float* __restrict__ x,
                                                   const float* __restrict__ fnw,
                                                   float* __restrict__ xn_buf) {
    int b = blockIdx.x;
    int tid = threadIdx.x;
    const float* xr = x + ((size_t)b * LL + (LL - 1)) * DD;
    __shared__ float sred[4];
    float v[3]; float ss = 0.f;
    for (int j = 0; j < 3; j++) { v[j] = xr[tid + j * 256]; ss += v[j] * v[j]; }
    for (int o = 1; o < 64; o <<= 1) ss += __shfl_xor(ss, o, 64);
    if ((tid & 63) == 0) sred[tid >> 6] = ss;
    __syncthreads();
    float scale = rsqrtf((sred[0] + sred[1] + sred[2] + sred[3]) / (float)DD + 1e-6f);
    for (int j = 0; j < 3; j++) {
        int c = tid + j * 256;
        xn_buf[(size_t)b * DD + c] = v[j] * scale * fnw[c];
    }
}

__global__ __launch_bounds__(256) void head_h1_k(const float* __restrict__ xn_buf,
                                                 const float* __restrict__ h1w,
                                                 const float* __restrict__ h1b,
                                                 float* __restrict__ h_buf) {
    int b  = blockIdx.x;
    int o0 = blockIdx.y * 64;
    int tid = threadIdx.x;
    __shared__ float sx[DD];
    for (int c = tid; c < DD; c += 256) sx[c] = xn_buf[(size_t)b * DD + c];
    __syncthreads();
    int wave = tid >> 6, lane = tid & 63;
    for (int j = 0; j < 16; j++) {
        int o = o0 + wave * 16 + j;
        const float* wrow = h1w + (size_t)o * DD;
        float acc = 0.f;
        for (int k = 0; k < 12; k++) {
            int c = lane + 64 * k;
            acc += wrow[c] * sx[c];
        }
        for (int off = 1; off < 64; off <<= 1) acc += __shfl_xor(acc, off, 64);
        if (lane == 0) h_buf[(size_t)b * DD + o] = acc + h1b[o];
    }
}

__global__ __launch_bounds__(256) void head_out_k(const float* __restrict__ h_buf,
                                                  const float* __restrict__ hnw,
                                                  const float* __restrict__ h2w,
                                                  const float* __restrict__ h2b,
                                                  float* __restrict__ out) {
    int b = blockIdx.x;
    int tid = threadIdx.x;
    __shared__ float hh[DD];
    __shared__ float sred[4];
    const float* hr = h_buf + (size_t)b * DD;
    float ss = 0.f;
    for (int c = tid; c < DD; c += 256) { float v = hr[c]; ss += v * v; }
    for (int o = 1; o < 64; o <<= 1) ss += __shfl_xor(ss, o, 64);
    if ((tid & 63) == 0) sred[tid >> 6] = ss;
    __syncthreads();
    float sc = rsqrtf((sred[0] + sred[1] + sred[2] + sred[3]) / (float)DD + 1e-6f);
    for (int c = tid; c < DD; c += 256) {
        float v = hr[c] * sc * hnw[c];
        hh[c] = 0.5f * v * (1.f + erff(v * 0.70710678118f));
    }
    __syncthreads();
    int w = tid >> 6, lane = tid & 63;
    for (int j = w; j < 10; j += 4) {
        float acc = 0.f;
        const float* wrow = h2w + (size_t)j * DD;
        for (int c = lane; c < DD; c += 64) acc += hh[c] * wrow[c];
        for (int o = 1; o < 64; o <<= 1) acc += __shfl_xor(acc, o, 64);
        if (lane == 0) out[b * 10 + j] = acc + h2b[j];
    }
}

// ----------------------------------------------------------------
extern "C" void kernel_launch(void* const* d_in, const int* in_sizes, int n_in,
                              void* d_out, int out_size, void* d_ws, size_t ws_size,
                              hipStream_t stream) {
    const float* x_in      = (const float*)d_in[0];
    const float* norm_w    = (const float*)d_in[1];
    const float* in_proj_w = (const float*)d_in[2];
    const float* conv_w    = (const float*)d_in[3];
    const float* conv_b    = (const float*)d_in[4];
    const float* x_proj_w  = (const float*)d_in[5];
    const float* dt_proj_w = (const float*)d_in[6];
    const float* dt_proj_b = (const float*)d_in[7];
    const float* A_log     = (const float*)d_in[8];
    const float* D_skip    = (const float*)d_in[9];
    const float* out_proj_w= (const float*)d_in[10];
    const float* fnw       = (const float*)d_in[11];
    const float* h1w       = (const float*)d_in[12];
    const float* h1b       = (const float*)d_in[13];
    const float* hnw       = (const float*)d_in[14];
    const float* h2w       = (const float*)d_in[15];
    const float* h2b       = (const float*)d_in[16];
    float* out = (float*)d_out;

    char* ws = (char*)d_ws;
    size_t off = 0;
    auto alloc = [&](size_t bytes) -> void* {
        void* p = ws + off;
        off += (bytes + 255) & ~(size_t)255;
        return p;
    };
    bf16* w_in  = (bf16*)alloc((size_t)N1 * 2);
    bf16* w_xp  = (bf16*)alloc((size_t)N2 * 2);
    bf16* w_dt  = (bf16*)alloc((size_t)N3 * 2);
    bf16* w_out = (bf16*)alloc((size_t)N4 * 2);
    bf16* xn_bf = (bf16*)alloc((size_t)MROWS * DD * 2);
    bf16* xz_bf = (bf16*)alloc((size_t)MROWS * 2 * DI * 2);
    bf16* xc_bf = (bf16*)alloc((size_t)MROWS * DI * 2);
    bf16* gz_bf = (bf16*)alloc((size_t)MROWS * DI * 2);
    float* xdbl = (float*)alloc((size_t)MROWS * NXP * 4);
    bf16* dt_bf = (bf16*)alloc((size_t)MROWS * DTPAD * 2);
    bf16* y_bf  = (bf16*)alloc((size_t)MROWS * DI * 2);
    float* x_buf= (float*)alloc((size_t)MROWS * DD * 4);
    float* Pbuf = (float*)alloc((size_t)NC * BB * DI * DSTATE * 4);
    float* Sbuf = (float*)alloc((size_t)NC * BB * DI * DSTATE * 4);
    float* H0buf= (float*)alloc((size_t)NC * BB * DI * DSTATE * 4);
    float* xnl  = (float*)alloc((size_t)BB * DD * 4);
    float* hbuf = (float*)alloc((size_t)BB * DD * 4);
    float* xp_part = (float*)alloc((size_t)KSPLIT * MROWS * NXP * 4);
    float* op_part = (float*)alloc((size_t)OPKS * MROWS * DD * 4);

    // all weight conversions in one launch
    {
        int ntot = N1 + N2 + N3 + N4;
        cvt_all_k<<<(ntot + 255) / 256, 256, 0, stream>>>(
            in_proj_w, x_proj_w, dt_proj_w, out_proj_w, w_in, w_xp, w_dt, w_out);
    }

    for (int i = 0; i < 4; i++) {
        const float* x_src = (i == 0) ? x_in : x_buf;
        // 1. rmsnorm (layer 0 only; later layers get xn_bf from fused op_reduce_norm)
        if (i == 0)
            rmsnorm_k<<<MROWS, 256, 0, stream>>>(x_src, norm_w, xn_bf);
        // 2. in_proj: (2048 x 3072), bf16 out
        gemm_bt<1><<<dim3(MROWS / 128, 3072 / 128), 256, 0, stream>>>(
            xn_bf, w_in + (size_t)i * 3072 * 768, nullptr, xz_bf,
            MROWS, 2 * DI, DD);
        // 3. causal conv + silu + silu(z) gate (bf16 outputs)
        conv_silu_k<<<(MROWS * (DI / 4) + 255) / 256, 256, 0, stream>>>(
            xz_bf, conv_w + (size_t)i * DI * 4, conv_b + (size_t)i * DI, xc_bf, gz_bf);
        // 4. x_proj split-K + reduce -> xdbl f32 + padded bf16 dt
        gemm_xp<<<dim3(MROWS / 64, KSPLIT), 256, 0, stream>>>(
            xc_bf, w_xp + (size_t)i * NXP * DI, xp_part);
        xp_reduce_k<<<(MROWS * NXP + 255) / 256, 256, 0, stream>>>(xp_part, xdbl, dt_bf);
        // 5. chunk-parallel 2-phase scan: local (P,S) -> compose -> rescan + emit
        scan1_k<<<dim3(DI / 16, BB, NC), 256, 0, stream>>>(
            dt_bf, w_dt + (size_t)i * DI * DTPAD, dt_proj_b + (size_t)i * DI,
            xc_bf, xdbl, A_log + (size_t)i * DI * DSTATE, Pbuf, Sbuf);
        compose_k<<<(BB * DI * DSTATE) / 256, 256, 0, stream>>>(Pbuf, Sbuf, H0buf);
        scan2_k<<<dim3(DI / 16, BB, NC), 256, 0, stream>>>(
            dt_bf, w_dt + (size_t)i * DI * DTPAD, dt_proj_b + (size_t)i * DI,
            xc_bf, gz_bf, xdbl, A_log + (size_t)i * DI * DSTATE,
            D_skip + (size_t)i * DI, H0buf, y_bf);
        // 6. out_proj split-K -> partials; fused reduce + residual + next rmsnorm
        gemm_bt<5><<<dim3(MROWS / 128, DD / 128, OPKS), 256, 0, stream>>>(
            y_bf, w_out + (size_t)i * DD * DI, op_part, nullptr,
            MROWS, DD, DI);
        op_reduce_norm_k<<<MROWS, 256, 0, stream>>>(
            op_part, x_src, norm_w + ((i + 1) & 3) * DD, x_buf, xn_bf);
    }

    head_norm_k<<<BB, 256, 0, stream>>>(x_buf, fnw, xnl);
    head_h1_k<<<dim3(BB, DD / 64), 256, 0, stream>>>(xnl, h1w, h1b, hbuf);
    head_out_k<<<BB, 256, 0, stream>>>(hbuf, hnw, h2w, h2b, out);
}